// Round 6
// baseline (238.319 us; speedup 1.0000x reference)
//
#include <hip/hip_runtime.h>

// Problem constants (match reference setup_inputs)
#define N_IN    512
#define NLAYERS 5
#define M_NODES 2048
#define FAN     32
#define B_BATCH 1024
#define E_EDGES (M_NODES * FAN)
#define N_TOTAL (N_IN + NLAYERS * M_NODES)   // 10752

// vals in BF16, sliced: [slice][node][SLICE_B] (8 slices x 128 batch).
// Row = 256 B; a HALF-wave (32 lanes x ushort4 = 8 B/lane) covers one row.
// R6: occupancy is the lever (R3 @32 waves/CU -> 10 TB/s vs R5 @16 -> 6 TB/s):
// NPB=8 -> 2048 blocks -> 8 blocks/CU -> 32 waves/CU, and small 2-VGPR loads
// so many independent gathers stay in flight within the 64-VGPR budget that
// __launch_bounds__(256,8) pins.
#define SLICES  8
#define SLICE_B 128                         // bf16 elems per row (256 B)
#define NPB     8                           // nodes per block (1 per half-wave)
#define GROUPS  (M_NODES / NPB)             // 256 -> grid 8*256 = 2048 blocks

typedef unsigned short u16;
typedef __attribute__((ext_vector_type(4))) unsigned short ushortx4;

__device__ __forceinline__ float bf2f(u16 u) {
    return __uint_as_float(((unsigned)u) << 16);
}
__device__ __forceinline__ u16 f2bf(float f) {   // round-to-nearest-even
    unsigned b = __float_as_uint(f);
    return (u16)((b + 0x7FFFu + ((b >> 16) & 1u)) >> 16);
}

// ---------------------------------------------------------------------------
// Transpose x (B, N_IN) fp32 batch-major -> bf16 sliced node-major
// grid (N_IN/32, B/32), block (32, 8)
// ---------------------------------------------------------------------------
__global__ void transpose_in_kernel(const float* __restrict__ x,
                                    u16* __restrict__ vals) {
    __shared__ float tile[32][33];
    const int tx = threadIdx.x;   // 0..31
    const int ty = threadIdx.y;   // 0..7
    const int n0 = blockIdx.x * 32;
    const int b0 = blockIdx.y * 32;
#pragma unroll
    for (int i = 0; i < 4; ++i) {
        int b = b0 + ty + i * 8;
        int n = n0 + tx;
        tile[ty + i * 8][tx] = x[(size_t)b * N_IN + n];   // coalesced in n
    }
    __syncthreads();
#pragma unroll
    for (int i = 0; i < 4; ++i) {
        int n  = n0 + ty + i * 8;
        int b  = b0 + tx;                 // 32 consecutive b -> same slice
        int sl = b >> 7;
        int bb = b & (SLICE_B - 1);
        vals[((size_t)sl * N_TOTAL + n) * SLICE_B + bb] =
            f2bf(tile[tx][ty + i * 8]);   // coalesced in bb
    }
}

// ---------------------------------------------------------------------------
// One DAG layer, one batch-slice per block (slice = blockIdx.x & 7):
//   out[j][bb] = relu(bias[j] + sum_k bf2f(vals[s][src[j*32+k]][bb]) * w[..])
// Block: 256 threads = 8 half-waves; half-wave nb owns node j=group*8+nb;
// lane covers 4 batch elems (ushort4 = 8 B). Edges staged in LDS (coalesced).
// ---------------------------------------------------------------------------
__global__ __launch_bounds__(256, 8) void layer_kernel(
    u16* __restrict__ vals,
    const int base,                              // N_IN + l*M (output node base)
    const int* __restrict__ src,                 // this layer's src_idx [E]
    const float* __restrict__ w,                 // this layer's weights [E]
    const float* __restrict__ bias) {            // this layer's biases [M]
    __shared__ int   s_src[NPB * FAN];           // 256
    __shared__ float s_w[NPB * FAN];

    const int slice = blockIdx.x & (SLICES - 1);
    const int group = blockIdx.x >> 3;           // node group (8 nodes)
    const int t     = threadIdx.x;
    const int nb    = t >> 5;                    // half-wave id 0..7 = node
    const int bb4   = (t & 31) * 4;              // batch offset (4 elems/lane)

    // stage this block's 256 edges (one coalesced dword load each)
    const int eblk = group * (NPB * FAN);
    s_src[t] = src[eblk + t];
    s_w[t]   = w[eblk + t];
    __syncthreads();

    u16* vslice = vals + (size_t)slice * N_TOTAL * SLICE_B;

    const int j = group * NPB + nb;
    const float bj = bias[j];
    float a0[4], a1[4];
#pragma unroll
    for (int i = 0; i < 4; ++i) { a0[i] = bj; a1[i] = 0.f; }

    const int kb = nb * FAN;
#pragma unroll
    for (int k = 0; k < FAN; k += 4) {
        const int   sA = s_src[kb + k];
        const int   sB = s_src[kb + k + 1];
        const int   sC = s_src[kb + k + 2];
        const int   sD = s_src[kb + k + 3];
        const float wA = s_w[kb + k];
        const float wB = s_w[kb + k + 1];
        const float wC = s_w[kb + k + 2];
        const float wD = s_w[kb + k + 3];
        const ushortx4 vA = *reinterpret_cast<const ushortx4*>(
            vslice + (size_t)sA * SLICE_B + bb4);
        const ushortx4 vB = *reinterpret_cast<const ushortx4*>(
            vslice + (size_t)sB * SLICE_B + bb4);
        const ushortx4 vC = *reinterpret_cast<const ushortx4*>(
            vslice + (size_t)sC * SLICE_B + bb4);
        const ushortx4 vD = *reinterpret_cast<const ushortx4*>(
            vslice + (size_t)sD * SLICE_B + bb4);
#pragma unroll
        for (int i = 0; i < 4; ++i) a0[i] = fmaf(wA, bf2f(vA[i]), a0[i]);
#pragma unroll
        for (int i = 0; i < 4; ++i) a1[i] = fmaf(wB, bf2f(vB[i]), a1[i]);
#pragma unroll
        for (int i = 0; i < 4; ++i) a0[i] = fmaf(wC, bf2f(vC[i]), a0[i]);
#pragma unroll
        for (int i = 0; i < 4; ++i) a1[i] = fmaf(wD, bf2f(vD[i]), a1[i]);
    }

    ushortx4 r;
#pragma unroll
    for (int i = 0; i < 4; ++i) r[i] = f2bf(fmaxf(a0[i] + a1[i], 0.f));
    *reinterpret_cast<ushortx4*>(
        vslice + (size_t)(base + j) * SLICE_B + bb4) = r;
}

// ---------------------------------------------------------------------------
// Sliced bf16 last-layer rows -> fp32 batch-major out[b*M + j]
// grid (M/32, B/32), block (32, 8)
// ---------------------------------------------------------------------------
__global__ void transpose_out_kernel(const u16* __restrict__ vals,
                                     float* __restrict__ out) {
    __shared__ float tile[32][33];
    const int tx = threadIdx.x;
    const int ty = threadIdx.y;
    const int j0 = blockIdx.x * 32;
    const int b0 = blockIdx.y * 32;
    const int node0 = N_IN + (NLAYERS - 1) * M_NODES;
#pragma unroll
    for (int i = 0; i < 4; ++i) {
        int j  = j0 + ty + i * 8;
        int b  = b0 + tx;                 // consecutive bb within one slice
        int sl = b >> 7;
        int bb = b & (SLICE_B - 1);
        tile[ty + i * 8][tx] =
            bf2f(vals[((size_t)sl * N_TOTAL + node0 + j) * SLICE_B + bb]);
    }
    __syncthreads();
#pragma unroll
    for (int i = 0; i < 4; ++i) {
        int b = b0 + ty + i * 8;
        int j = j0 + tx;
        out[(size_t)b * M_NODES + j] = tile[tx][ty + i * 8];       // coalesced
    }
}

extern "C" void kernel_launch(void* const* d_in, const int* in_sizes, int n_in,
                              void* d_out, int out_size, void* d_ws, size_t ws_size,
                              hipStream_t stream) {
    const float* x       = (const float*)d_in[0];   // (B, N_IN)
    const float* weights = (const float*)d_in[1];   // (L, E)
    const float* biases  = (const float*)d_in[2];   // (L, M)
    const int*   src_idx = (const int*)d_in[3];     // (L, E)
    // d_in[4] = dst_idx: structurally repeat(arange(M), FAN) -> segment j = e/FAN
    float* out = (float*)d_out;                     // (B, M) batch-major fp32
    u16*  vals = (u16*)d_ws;                        // [8][N_TOTAL][128] bf16, 22 MB

    // 1) inputs -> sliced bf16 node-major vals
    transpose_in_kernel<<<dim3(N_IN / 32, B_BATCH / 32), dim3(32, 8), 0, stream>>>(
        x, vals);

    // 2) layers (sequential launches = topological sync)
    // blocks = SLICES * GROUPS = 2048 -> 8 blocks/CU, 32 waves/CU (max)
    for (int l = 0; l < NLAYERS; ++l) {
        layer_kernel<<<SLICES * GROUPS, 256, 0, stream>>>(
            vals, N_IN + l * M_NODES,
            src_idx + (size_t)l * E_EDGES,
            weights + (size_t)l * E_EDGES,
            biases  + (size_t)l * M_NODES);
    }

    // 3) last layer bf16 rows -> fp32 batch-major output
    transpose_out_kernel<<<dim3(M_NODES / 32, B_BATCH / 32), dim3(32, 8), 0, stream>>>(
        vals, out);
}

// Round 7
// 90.524 us; speedup vs baseline: 2.6327x; 2.6327x over previous
//
#include <hip/hip_runtime.h>

// Problem constants (match reference setup_inputs)
#define N_IN    512
#define NLAYERS 5
#define M_NODES 2048
#define FAN     32
#define B_BATCH 1024
#define E_EDGES (M_NODES * FAN)              // 65536
#define N_TOTAL (N_IN + NLAYERS * M_NODES)   // 10752

// R7: persistent per-CU design. One block = one CU = batch chunk of C=4.
// ALL node activations live in LDS as 4xbf16 (8 B/node = 84 KB total, which
// also guarantees 1 block/CU). The 5 layers run inside one kernel with
// __syncthreads() between layers — gathers hit LDS (per-CU, scalable BW)
// instead of the saturated ~10 TB/s L2/L3 path; edges stream contiguously.
#define CB      4                            // batch per block
#define NBLK    (B_BATCH / CB)               // 256 blocks
#define GROUPS  (M_NODES / 64)               // 32 node-groups of 64
#define ECH     (FAN / 4)                    // 8 edge-chunks of 4
#define LDS_BYTES (N_TOTAL * 8)              // 86016

typedef unsigned short u16;
typedef unsigned int   u32;

__device__ __forceinline__ u16 f2bf(float f) {   // round-to-nearest-even
    u32 b = __float_as_uint(f);
    return (u16)((b + 0x7FFFu + ((b >> 16) & 1u)) >> 16);
}

// ---------------------------------------------------------------------------
// Pack edges: pck[l][g][ec][lane][c], word = (bf16(w) << 16) | u16(src).
// Lane-major inner layout so the net kernel's per-lane uint4 loads are
// coalesced (64 lanes x 16 B = 1 KB per instruction).
// ---------------------------------------------------------------------------
__global__ __launch_bounds__(1024) void pack_edges(
    const float* __restrict__ w,             // (L, E)
    const int* __restrict__ src,             // (L, E)
    u32* __restrict__ pck) {
    const int d = blockIdx.x * 1024 + threadIdx.x;   // 0 .. L*E-1
    if (d >= NLAYERS * E_EDGES) return;
    const int l    = d >> 16;                // / 65536
    const int r    = d & 65535;
    const int g    = r >> 11;                // 2048 words per group
    const int ec   = (r & 2047) >> 8;        // 256 words per ec
    const int lane = (r & 255) >> 2;
    const int c    = r & 3;
    const int j = g * 64 + lane;
    const int k = ec * 4 + c;
    const size_t e = (size_t)l * E_EDGES + j * FAN + k;
    pck[d] = ((u32)f2bf(w[e]) << 16) | (u32)(u16)src[e];
}

// ---------------------------------------------------------------------------
// Persistent network kernel. Block blk owns batch rows 4*blk .. 4*blk+3.
// LDS vals: node n -> uint2 at [n] = {bf16(b0)|bf16(b1)<<16, bf16(b2)|bf16(b3)<<16}.
// Per layer: 2 rounds x 1024 threads = 2048 nodes; thread computes one node:
//   8 coalesced uint4 edge loads -> 32 x (unpack + ds_read_b64 + 4 fma).
// Layer 4 results go straight to global (batch-major), never stored in LDS.
// ---------------------------------------------------------------------------
__global__ __launch_bounds__(1024) void net_kernel(
    const float* __restrict__ x,             // (B, N_IN) fp32
    const u32* __restrict__ pck,             // packed edges
    const float* __restrict__ bias,          // (L, M) fp32
    float* __restrict__ out) {               // (B, M) fp32
    extern __shared__ u32 vals[];            // [N_TOTAL][2] words
    uint2* vals2 = reinterpret_cast<uint2*>(vals);

    const int t   = threadIdx.x;
    const int blk = blockIdx.x;
    const int lane6 = t & 63;

    // stage this block's 4 input rows (coalesced across t per row)
    if (t < N_IN) {
        const float v0 = x[(size_t)(4 * blk + 0) * N_IN + t];
        const float v1 = x[(size_t)(4 * blk + 1) * N_IN + t];
        const float v2 = x[(size_t)(4 * blk + 2) * N_IN + t];
        const float v3 = x[(size_t)(4 * blk + 3) * N_IN + t];
        vals2[t] = make_uint2((u32)f2bf(v0) | ((u32)f2bf(v1) << 16),
                              (u32)f2bf(v2) | ((u32)f2bf(v3) << 16));
    }

    for (int l = 0; l < NLAYERS; ++l) {
        __syncthreads();
        const int base = N_IN + l * M_NODES;
#pragma unroll
        for (int r = 0; r < 2; ++r) {
            const int j = r * 1024 + t;
            const int g = j >> 6;
            const uint4* ep = reinterpret_cast<const uint4*>(pck) +
                              ((size_t)((l * GROUPS + g) * ECH) * 64 + lane6);
            const float bj = bias[l * M_NODES + j];
            float a0 = bj, a1 = bj, a2 = bj, a3 = bj;
#pragma unroll
            for (int ec = 0; ec < ECH; ++ec) {
                const uint4 wd = ep[(size_t)ec * 64];
                const u32 words[4] = {wd.x, wd.y, wd.z, wd.w};
#pragma unroll
                for (int c = 0; c < 4; ++c) {
                    const u32 word = words[c];
                    const u32 s    = word & 0xFFFFu;
                    const float wv = __uint_as_float(word & 0xFFFF0000u);
                    const uint2 v  = vals2[s];               // ds_read_b64
                    a0 = fmaf(wv, __uint_as_float(v.x << 16),          a0);
                    a1 = fmaf(wv, __uint_as_float(v.x & 0xFFFF0000u), a1);
                    a2 = fmaf(wv, __uint_as_float(v.y << 16),          a2);
                    a3 = fmaf(wv, __uint_as_float(v.y & 0xFFFF0000u), a3);
                }
            }
            a0 = fmaxf(a0, 0.f);
            a1 = fmaxf(a1, 0.f);
            a2 = fmaxf(a2, 0.f);
            a3 = fmaxf(a3, 0.f);
            if (l < NLAYERS - 1) {
                vals2[base + j] =
                    make_uint2((u32)f2bf(a0) | ((u32)f2bf(a1) << 16),
                               (u32)f2bf(a2) | ((u32)f2bf(a3) << 16));
            } else {
                out[(size_t)(4 * blk + 0) * M_NODES + j] = a0;
                out[(size_t)(4 * blk + 1) * M_NODES + j] = a1;
                out[(size_t)(4 * blk + 2) * M_NODES + j] = a2;
                out[(size_t)(4 * blk + 3) * M_NODES + j] = a3;
            }
        }
    }
}

extern "C" void kernel_launch(void* const* d_in, const int* in_sizes, int n_in,
                              void* d_out, int out_size, void* d_ws, size_t ws_size,
                              hipStream_t stream) {
    const float* x       = (const float*)d_in[0];   // (B, N_IN)
    const float* weights = (const float*)d_in[1];   // (L, E)
    const float* biases  = (const float*)d_in[2];   // (L, M)
    const int*   src_idx = (const int*)d_in[3];     // (L, E)
    // d_in[4] = dst_idx: structurally repeat(arange(M), FAN) -> segment j = e/FAN
    float* out = (float*)d_out;                     // (B, M) fp32
    u32*   pck = (u32*)d_ws;                        // packed edges, 2.62 MB

    // 1) pack edges (re-done every call; d_ws is re-poisoned by the harness)
    pack_edges<<<(NLAYERS * E_EDGES + 1023) / 1024, 1024, 0, stream>>>(
        weights, src_idx, pck);

    // 2) persistent per-CU network. Dynamic LDS 84 KB needs the opt-in
    //    (host-eager property call — not a stream op, graph-capture safe).
    static bool attr_done = [] {
        hipFuncSetAttribute(reinterpret_cast<const void*>(net_kernel),
                            hipFuncAttributeMaxDynamicSharedMemorySize,
                            LDS_BYTES);
        return true;
    }();
    (void)attr_done;
    hipFuncSetAttribute(reinterpret_cast<const void*>(net_kernel),
                        hipFuncAttributeMaxDynamicSharedMemorySize, LDS_BYTES);
    net_kernel<<<NBLK, 1024, LDS_BYTES, stream>>>(x, pck, biases, out);
}